// Round 1
// baseline (762.919 us; speedup 1.0000x reference)
//
#include <hip/hip_runtime.h>

#define IN_C  128
#define HID_C 128
#define OUT_C 64

// ---- graph prep ------------------------------------------------------------

__global__ void deg_kernel(const int* __restrict__ dst, int* __restrict__ deg, int E) {
    int e = blockIdx.x * blockDim.x + threadIdx.x;
    if (e < E) atomicAdd(&deg[dst[e]], 1);
}

__global__ void dinv_kernel(const int* __restrict__ deg, float* __restrict__ dinv, int n) {
    int i = blockIdx.x * blockDim.x + threadIdx.x;
    if (i < n) dinv[i] = rsqrtf((float)(deg[i] + 1));  // +1: self-loop
}

// single-block exclusive scan over deg[0..n) -> rowptr[0..n]
__global__ void scan_kernel(const int* __restrict__ deg, int* __restrict__ rowptr, int n) {
    __shared__ int sums[1024];
    int t = threadIdx.x;
    int chunk = (n + 1023) >> 10;
    int beg = t * chunk;
    int end = min(beg + chunk, n);
    int s = 0;
    for (int i = beg; i < end; ++i) s += deg[i];
    sums[t] = s;
    __syncthreads();
    for (int off = 1; off < 1024; off <<= 1) {
        int v = (t >= off) ? sums[t - off] : 0;
        __syncthreads();
        sums[t] += v;
        __syncthreads();
    }
    int run = (t == 0) ? 0 : sums[t - 1];
    for (int i = beg; i < end; ++i) { rowptr[i] = run; run += deg[i]; }
    if (t == 1023) rowptr[n] = sums[1023];  // == E
}

__global__ void scatter_kernel(const int* __restrict__ src, const int* __restrict__ dst,
                               const int* __restrict__ rowptr, int* __restrict__ cursor,
                               int* __restrict__ col, int E) {
    int e = blockIdx.x * blockDim.x + threadIdx.x;
    if (e < E) {
        int d = dst[e];
        int pos = rowptr[d] + atomicAdd(&cursor[d], 1);
        col[pos] = src[e];
    }
}

// ---- dense transform: Hs[r][c] = dinv[r] * sum_k X[r][k] * W[k][c0+c] ------
// block = 256 threads (16 col-thr x 16 row-thr), tile 64 rows x 64 cols,
// 4x4 register tile per thread, K=128 fixed. X width is always 128.

__global__ __launch_bounds__(256) void mm_kernel(
    const float* __restrict__ X, const float* __restrict__ W,
    const float* __restrict__ dinv, float* __restrict__ Hs,
    int n, int outc) {
    __shared__ float xs[64 * 128];   // 32 KB
    __shared__ float ws[128 * 64];   // 32 KB
    int t = threadIdx.x;
    int row0 = blockIdx.x * 64;
    int c0 = blockIdx.y * 64;

    for (int i = t; i < (64 * 128) / 4; i += 256) {
        int idx = i * 4;
        int r = idx >> 7, k = idx & 127;
        int row = row0 + r;
        float4 v = make_float4(0.f, 0.f, 0.f, 0.f);
        if (row < n) v = *(const float4*)&X[(size_t)row * 128 + k];
        *(float4*)&xs[idx] = v;
    }
    for (int i = t; i < (128 * 64) / 4; i += 256) {
        int idx = i * 4;
        int k = idx >> 6, c = idx & 63;
        *(float4*)&ws[idx] = *(const float4*)&W[(size_t)k * outc + c0 + c];
    }
    __syncthreads();

    int tc = t & 15, tr = t >> 4;
    int r0 = tr * 4, cc = tc * 4;
    float acc[4][4] = {};
    for (int k = 0; k < 128; k += 4) {
        float4 xv[4], wv[4];
#pragma unroll
        for (int i = 0; i < 4; ++i) xv[i] = *(const float4*)&xs[(r0 + i) * 128 + k];
#pragma unroll
        for (int j = 0; j < 4; ++j) wv[j] = *(const float4*)&ws[(k + j) * 64 + cc];
#pragma unroll
        for (int i = 0; i < 4; ++i) {
            acc[i][0] += xv[i].x * wv[0].x + xv[i].y * wv[1].x + xv[i].z * wv[2].x + xv[i].w * wv[3].x;
            acc[i][1] += xv[i].x * wv[0].y + xv[i].y * wv[1].y + xv[i].z * wv[2].y + xv[i].w * wv[3].y;
            acc[i][2] += xv[i].x * wv[0].z + xv[i].y * wv[1].z + xv[i].z * wv[2].z + xv[i].w * wv[3].z;
            acc[i][3] += xv[i].x * wv[0].w + xv[i].y * wv[1].w + xv[i].z * wv[2].w + xv[i].w * wv[3].w;
        }
    }
#pragma unroll
    for (int i = 0; i < 4; ++i) {
        int row = row0 + r0 + i;
        if (row < n) {
            float s = dinv[row];
            float4 o = make_float4(s * acc[i][0], s * acc[i][1], s * acc[i][2], s * acc[i][3]);
            *(float4*)&Hs[(size_t)row * outc + c0 + cc] = o;
        }
    }
}

// ---- aggregation: out[d] = dinv[d]*(Hs[d] + sum_{s in N(d)} Hs[s]) + b -----
// one block per node, thread = channel; 4-wide neighbor unroll for MLP.

__global__ void agg_kernel(const float* __restrict__ Hs, const float* __restrict__ bias,
                           const float* __restrict__ dinv, const int* __restrict__ rowptr,
                           const int* __restrict__ col, float* __restrict__ out,
                           int C, int relu) {
    int d = blockIdx.x;
    int c = threadIdx.x;
    float acc = Hs[(size_t)d * C + c];
    int beg = rowptr[d], end = rowptr[d + 1];
    int j = beg;
    for (; j + 4 <= end; j += 4) {
        int s0 = col[j], s1 = col[j + 1], s2 = col[j + 2], s3 = col[j + 3];
        float a0 = Hs[(size_t)s0 * C + c];
        float a1 = Hs[(size_t)s1 * C + c];
        float a2 = Hs[(size_t)s2 * C + c];
        float a3 = Hs[(size_t)s3 * C + c];
        acc += a0 + a1 + a2 + a3;
    }
    for (; j < end; ++j) acc += Hs[(size_t)col[j] * C + c];
    float v = dinv[d] * acc + bias[c];
    if (relu) v = fmaxf(v, 0.f);
    out[(size_t)d * C + c] = v;
}

// ---- driver ----------------------------------------------------------------

extern "C" void kernel_launch(void* const* d_in, const int* in_sizes, int n_in,
                              void* d_out, int out_size, void* d_ws, size_t ws_size,
                              hipStream_t stream) {
    const float* x  = (const float*)d_in[0];
    const int*   ei = (const int*)d_in[1];
    const float* W1 = (const float*)d_in[2];
    const float* b1 = (const float*)d_in[3];
    const float* W2 = (const float*)d_in[4];
    const float* b2 = (const float*)d_in[5];
    float* out = (float*)d_out;

    int N = in_sizes[0] / IN_C;
    int E = in_sizes[1] / 2;
    const int* src = ei;
    const int* dst = ei + E;

    char* ws = (char*)d_ws;
    size_t off = 0;
    int*   deg    = (int*)(ws + off);   off += (size_t)N * 4;
    int*   cursor = (int*)(ws + off);   off += (size_t)N * 4;   // contiguous with deg
    float* dinv   = (float*)(ws + off); off += (size_t)N * 4;
    int*   rowptr = (int*)(ws + off);   off += (size_t)(N + 1) * 4;
    off = (off + 15) & ~(size_t)15;
    int*   col    = (int*)(ws + off);   off += (size_t)E * 4;
    off = (off + 15) & ~(size_t)15;
    float* H1     = (float*)(ws + off); off += (size_t)N * HID_C * 4;
    float* AG1    = (float*)(ws + off); off += (size_t)N * HID_C * 4;
    float* H2     = H1;  // H1 dead after agg1; reuse for layer-2 transform

    hipMemsetAsync(deg, 0, (size_t)N * 8, stream);  // zeros deg + cursor

    const int tpb = 256;
    deg_kernel<<<(E + tpb - 1) / tpb, tpb, 0, stream>>>(dst, deg, E);
    dinv_kernel<<<(N + tpb - 1) / tpb, tpb, 0, stream>>>(deg, dinv, N);
    scan_kernel<<<1, 1024, 0, stream>>>(deg, rowptr, N);
    scatter_kernel<<<(E + tpb - 1) / tpb, tpb, 0, stream>>>(src, dst, rowptr, cursor, col, E);

    dim3 g1((N + 63) / 64, HID_C / 64);
    mm_kernel<<<g1, 256, 0, stream>>>(x, W1, dinv, H1, N, HID_C);
    agg_kernel<<<N, HID_C, 0, stream>>>(H1, b1, dinv, rowptr, col, AG1, HID_C, 1);

    dim3 g2((N + 63) / 64, OUT_C / 64);
    mm_kernel<<<g2, 256, 0, stream>>>(AG1, W2, dinv, H2, N, OUT_C);
    agg_kernel<<<N, OUT_C, 0, stream>>>(H2, b2, dinv, rowptr, col, out, OUT_C, 0);
}

// Round 2
// 592.380 us; speedup vs baseline: 1.2879x; 1.2879x over previous
//
#include <hip/hip_runtime.h>

#define IN_C  128
#define HID_C 128
#define OUT_C 64
#define SCAN_ELEMS 1024   // elements per scan block (256 thr x 4)

// ---- graph prep ------------------------------------------------------------

__global__ void deg_kernel(const int* __restrict__ dst, int* __restrict__ deg, int E) {
    int e = blockIdx.x * blockDim.x + threadIdx.x;
    if (e < E) atomicAdd(&deg[dst[e]], 1);
}

__global__ void dinv_kernel(const int* __restrict__ deg, float* __restrict__ dinv, int n) {
    int i = blockIdx.x * blockDim.x + threadIdx.x;
    if (i < n) dinv[i] = rsqrtf((float)(deg[i] + 1));  // +1: self-loop
}

// hierarchical exclusive scan: pass 1 — per-block scan + block sums
__global__ __launch_bounds__(256) void scan1_kernel(const int* __restrict__ deg,
                                                    int* __restrict__ rowptr,
                                                    int* __restrict__ bsum, int n) {
    __shared__ int tsum[256];
    int t = threadIdx.x;
    int base = blockIdx.x * SCAN_ELEMS + t * 4;
    int v[4];
#pragma unroll
    for (int k = 0; k < 4; ++k) v[k] = (base + k < n) ? deg[base + k] : 0;
    tsum[t] = v[0] + v[1] + v[2] + v[3];
    __syncthreads();
    for (int off = 1; off < 256; off <<= 1) {
        int x = (t >= off) ? tsum[t - off] : 0;
        __syncthreads();
        tsum[t] += x;
        __syncthreads();
    }
    int run = (t == 0) ? 0 : tsum[t - 1];
#pragma unroll
    for (int k = 0; k < 4; ++k) {
        if (base + k < n) rowptr[base + k] = run;
        run += v[k];
    }
    if (t == 255) bsum[blockIdx.x] = tsum[255];
}

// pass 2 — single-block exclusive scan of block sums (nb <= 1024); bsum[nb]=total
__global__ __launch_bounds__(1024) void scan2_kernel(int* __restrict__ bsum, int nb) {
    __shared__ int sh[1024];
    int t = threadIdx.x;
    sh[t] = (t < nb) ? bsum[t] : 0;
    __syncthreads();
    for (int off = 1; off < 1024; off <<= 1) {
        int x = (t >= off) ? sh[t - off] : 0;
        __syncthreads();
        sh[t] += x;
        __syncthreads();
    }
    if (t < nb) bsum[t] = (t == 0) ? 0 : sh[t - 1];
    if (t == 0) bsum[nb] = sh[nb - 1];
}

// pass 3 — add block offsets; finalize rowptr[n]
__global__ __launch_bounds__(256) void scan3_kernel(int* __restrict__ rowptr,
                                                    const int* __restrict__ bsum,
                                                    int n, int nb) {
    int t = threadIdx.x;
    int base = blockIdx.x * SCAN_ELEMS + t * 4;
    int off = bsum[blockIdx.x];
#pragma unroll
    for (int k = 0; k < 4; ++k)
        if (base + k < n) rowptr[base + k] += off;
    if (blockIdx.x == 0 && t == 0) rowptr[n] = bsum[nb];
}

__global__ void scatter_kernel(const int* __restrict__ src, const int* __restrict__ dst,
                               const int* __restrict__ rowptr, int* __restrict__ cursor,
                               int* __restrict__ col, int E) {
    int e = blockIdx.x * blockDim.x + threadIdx.x;
    if (e < E) {
        int d = dst[e];
        int pos = rowptr[d] + atomicAdd(&cursor[d], 1);
        col[pos] = src[e];
    }
}

// ---- dense transform: Hs[r][c] = dinv[r] * sum_k X[r][k] * W[k][c0+c] ------

__global__ __launch_bounds__(256) void mm_kernel(
    const float* __restrict__ X, const float* __restrict__ W,
    const float* __restrict__ dinv, float* __restrict__ Hs,
    int n, int outc) {
    __shared__ float xs[64 * 128];   // 32 KB
    __shared__ float ws[128 * 64];   // 32 KB
    int t = threadIdx.x;
    int row0 = blockIdx.x * 64;
    int c0 = blockIdx.y * 64;

    for (int i = t; i < (64 * 128) / 4; i += 256) {
        int idx = i * 4;
        int r = idx >> 7, k = idx & 127;
        int row = row0 + r;
        float4 v = make_float4(0.f, 0.f, 0.f, 0.f);
        if (row < n) v = *(const float4*)&X[(size_t)row * 128 + k];
        *(float4*)&xs[idx] = v;
    }
    for (int i = t; i < (128 * 64) / 4; i += 256) {
        int idx = i * 4;
        int k = idx >> 6, c = idx & 63;
        *(float4*)&ws[idx] = *(const float4*)&W[(size_t)k * outc + c0 + c];
    }
    __syncthreads();

    int tc = t & 15, tr = t >> 4;
    int r0 = tr * 4, cc = tc * 4;
    float acc[4][4] = {};
    for (int k = 0; k < 128; k += 4) {
        float4 xv[4], wv[4];
#pragma unroll
        for (int i = 0; i < 4; ++i) xv[i] = *(const float4*)&xs[(r0 + i) * 128 + k];
#pragma unroll
        for (int j = 0; j < 4; ++j) wv[j] = *(const float4*)&ws[(k + j) * 64 + cc];
#pragma unroll
        for (int i = 0; i < 4; ++i) {
            acc[i][0] += xv[i].x * wv[0].x + xv[i].y * wv[1].x + xv[i].z * wv[2].x + xv[i].w * wv[3].x;
            acc[i][1] += xv[i].x * wv[0].y + xv[i].y * wv[1].y + xv[i].z * wv[2].y + xv[i].w * wv[3].y;
            acc[i][2] += xv[i].x * wv[0].z + xv[i].y * wv[1].z + xv[i].z * wv[2].z + xv[i].w * wv[3].z;
            acc[i][3] += xv[i].x * wv[0].w + xv[i].y * wv[1].w + xv[i].z * wv[2].w + xv[i].w * wv[3].w;
        }
    }
#pragma unroll
    for (int i = 0; i < 4; ++i) {
        int row = row0 + r0 + i;
        if (row < n) {
            float s = dinv[row];
            float4 o = make_float4(s * acc[i][0], s * acc[i][1], s * acc[i][2], s * acc[i][3]);
            *(float4*)&Hs[(size_t)row * outc + c0 + cc] = o;
        }
    }
}

// ---- aggregation: out[d] = dinv[d]*(Hs[d] + sum_{s in N(d)} Hs[s]) + b -----

__global__ void agg_kernel(const float* __restrict__ Hs, const float* __restrict__ bias,
                           const float* __restrict__ dinv, const int* __restrict__ rowptr,
                           const int* __restrict__ col, float* __restrict__ out,
                           int C, int relu) {
    int d = blockIdx.x;
    int c = threadIdx.x;
    float acc = Hs[(size_t)d * C + c];
    int beg = rowptr[d], end = rowptr[d + 1];
    int j = beg;
    for (; j + 4 <= end; j += 4) {
        int s0 = col[j], s1 = col[j + 1], s2 = col[j + 2], s3 = col[j + 3];
        float a0 = Hs[(size_t)s0 * C + c];
        float a1 = Hs[(size_t)s1 * C + c];
        float a2 = Hs[(size_t)s2 * C + c];
        float a3 = Hs[(size_t)s3 * C + c];
        acc += a0 + a1 + a2 + a3;
    }
    for (; j < end; ++j) acc += Hs[(size_t)col[j] * C + c];
    float v = dinv[d] * acc + bias[c];
    if (relu) v = fmaxf(v, 0.f);
    out[(size_t)d * C + c] = v;
}

// ---- driver ----------------------------------------------------------------

extern "C" void kernel_launch(void* const* d_in, const int* in_sizes, int n_in,
                              void* d_out, int out_size, void* d_ws, size_t ws_size,
                              hipStream_t stream) {
    const float* x  = (const float*)d_in[0];
    const int*   ei = (const int*)d_in[1];
    const float* W1 = (const float*)d_in[2];
    const float* b1 = (const float*)d_in[3];
    const float* W2 = (const float*)d_in[4];
    const float* b2 = (const float*)d_in[5];
    float* out = (float*)d_out;

    int N = in_sizes[0] / IN_C;
    int E = in_sizes[1] / 2;
    const int* src = ei;
    const int* dst = ei + E;

    int nb = (N + SCAN_ELEMS - 1) / SCAN_ELEMS;   // scan blocks (98 for N=100k)

    char* ws = (char*)d_ws;
    size_t off = 0;
    int*   deg    = (int*)(ws + off);   off += (size_t)N * 4;
    int*   cursor = (int*)(ws + off);   off += (size_t)N * 4;   // contiguous with deg
    float* dinv   = (float*)(ws + off); off += (size_t)N * 4;
    int*   rowptr = (int*)(ws + off);   off += (size_t)(N + 1) * 4;
    off = (off + 15) & ~(size_t)15;
    int*   bsum   = (int*)(ws + off);   off += (size_t)(nb + 1) * 4;
    off = (off + 15) & ~(size_t)15;
    int*   col    = (int*)(ws + off);   off += (size_t)E * 4;
    off = (off + 15) & ~(size_t)15;
    float* H1     = (float*)(ws + off); off += (size_t)N * HID_C * 4;
    float* AG1    = (float*)(ws + off); off += (size_t)N * HID_C * 4;
    float* H2     = H1;  // H1 dead after agg1; reuse for layer-2 transform

    hipMemsetAsync(deg, 0, (size_t)N * 8, stream);  // zeros deg + cursor

    const int tpb = 256;
    deg_kernel<<<(E + tpb - 1) / tpb, tpb, 0, stream>>>(dst, deg, E);
    dinv_kernel<<<(N + tpb - 1) / tpb, tpb, 0, stream>>>(deg, dinv, N);
    scan1_kernel<<<nb, 256, 0, stream>>>(deg, rowptr, bsum, N);
    scan2_kernel<<<1, 1024, 0, stream>>>(bsum, nb);
    scan3_kernel<<<nb, 256, 0, stream>>>(rowptr, bsum, N, nb);
    scatter_kernel<<<(E + tpb - 1) / tpb, tpb, 0, stream>>>(src, dst, rowptr, cursor, col, E);

    dim3 g1((N + 63) / 64, HID_C / 64);
    mm_kernel<<<g1, 256, 0, stream>>>(x, W1, dinv, H1, N, HID_C);
    agg_kernel<<<N, HID_C, 0, stream>>>(H1, b1, dinv, rowptr, col, AG1, HID_C, 1);

    dim3 g2((N + 63) / 64, OUT_C / 64);
    mm_kernel<<<g2, 256, 0, stream>>>(AG1, W2, dinv, H2, N, OUT_C);
    agg_kernel<<<N, OUT_C, 0, stream>>>(H2, b2, dinv, rowptr, col, out, OUT_C, 0);
}

// Round 5
// 505.896 us; speedup vs baseline: 1.5081x; 1.1710x over previous
//
#include <hip/hip_runtime.h>

#define IN_C  128
#define HID_C 128
#define OUT_C 64
#define SCAN_ELEMS 1024   // elements per scan block (256 thr x 4)

__device__ __forceinline__ unsigned short f2bf(float f) {
    unsigned u = __float_as_uint(f);
    unsigned r = (u + 0x7FFFu + ((u >> 16) & 1u)) >> 16;
    return (unsigned short)r;
}
__device__ __forceinline__ float bf_lo(unsigned u) { return __uint_as_float(u << 16); }
__device__ __forceinline__ float bf_hi(unsigned u) { return __uint_as_float(u & 0xFFFF0000u); }

// ---- graph prep ------------------------------------------------------------

__global__ void deg_kernel(const int* __restrict__ dst, int* __restrict__ deg, int E) {
    int e = blockIdx.x * blockDim.x + threadIdx.x;
    if (e < E) atomicAdd(&deg[dst[e]], 1);
}

__global__ void dinv_kernel(const int* __restrict__ deg, float* __restrict__ dinv, int n) {
    int i = blockIdx.x * blockDim.x + threadIdx.x;
    if (i < n) dinv[i] = rsqrtf((float)(deg[i] + 1));  // +1: self-loop
}

__global__ __launch_bounds__(256) void scan1_kernel(const int* __restrict__ deg,
                                                    int* __restrict__ rowptr,
                                                    int* __restrict__ bsum, int n) {
    __shared__ int tsum[256];
    int t = threadIdx.x;
    int base = blockIdx.x * SCAN_ELEMS + t * 4;
    int v[4];
#pragma unroll
    for (int k = 0; k < 4; ++k) v[k] = (base + k < n) ? deg[base + k] : 0;
    tsum[t] = v[0] + v[1] + v[2] + v[3];
    __syncthreads();
    for (int off = 1; off < 256; off <<= 1) {
        int x = (t >= off) ? tsum[t - off] : 0;
        __syncthreads();
        tsum[t] += x;
        __syncthreads();
    }
    int run = (t == 0) ? 0 : tsum[t - 1];
#pragma unroll
    for (int k = 0; k < 4; ++k) {
        if (base + k < n) rowptr[base + k] = run;
        run += v[k];
    }
    if (t == 255) bsum[blockIdx.x] = tsum[255];
}

__global__ __launch_bounds__(1024) void scan2_kernel(int* __restrict__ bsum, int nb) {
    __shared__ int sh[1024];
    int t = threadIdx.x;
    sh[t] = (t < nb) ? bsum[t] : 0;
    __syncthreads();
    for (int off = 1; off < 1024; off <<= 1) {
        int x = (t >= off) ? sh[t - off] : 0;
        __syncthreads();
        sh[t] += x;
        __syncthreads();
    }
    if (t < nb) bsum[t] = (t == 0) ? 0 : sh[t - 1];
    if (t == 0) bsum[nb] = sh[nb - 1];
}

__global__ __launch_bounds__(256) void scan3_kernel(int* __restrict__ rowptr,
                                                    const int* __restrict__ bsum,
                                                    int n, int nb) {
    int t = threadIdx.x;
    int base = blockIdx.x * SCAN_ELEMS + t * 4;
    int off = bsum[blockIdx.x];
#pragma unroll
    for (int k = 0; k < 4; ++k)
        if (base + k < n) rowptr[base + k] += off;
    if (blockIdx.x == 0 && t == 0) rowptr[n] = bsum[nb];
}

__global__ void scatter_kernel(const int* __restrict__ src, const int* __restrict__ dst,
                               const int* __restrict__ rowptr, int* __restrict__ cursor,
                               int* __restrict__ col, int E) {
    int e = blockIdx.x * blockDim.x + threadIdx.x;
    if (e < E) {
        int d = dst[e];
        int pos = rowptr[d] + atomicAdd(&cursor[d], 1);
        col[pos] = src[e];
    }
}

// ---- dense transform: Hs[r][c] = bf16( dinv[r] * sum_k X[r][k] * W[k][c] ) -

__global__ __launch_bounds__(256) void mm_kernel(
    const float* __restrict__ X, const float* __restrict__ W,
    const float* __restrict__ dinv, unsigned short* __restrict__ Hs,
    int n, int outc) {
    __shared__ float xs[64 * 128];   // 32 KB
    __shared__ float ws[128 * 64];   // 32 KB
    int t = threadIdx.x;
    int row0 = blockIdx.x * 64;
    int c0 = blockIdx.y * 64;

    for (int i = t; i < (64 * 128) / 4; i += 256) {
        int idx = i * 4;
        int r = idx >> 7, k = idx & 127;
        int row = row0 + r;
        float4 v = make_float4(0.f, 0.f, 0.f, 0.f);
        if (row < n) v = *(const float4*)&X[(size_t)row * 128 + k];
        *(float4*)&xs[idx] = v;
    }
    for (int i = t; i < (128 * 64) / 4; i += 256) {
        int idx = i * 4;
        int k = idx >> 6, c = idx & 63;
        *(float4*)&ws[idx] = *(const float4*)&W[(size_t)k * outc + c0 + c];
    }
    __syncthreads();

    int tc = t & 15, tr = t >> 4;
    int r0 = tr * 4, cc = tc * 4;
    float acc[4][4] = {};
    for (int k = 0; k < 128; k += 4) {
        float4 xv[4], wv[4];
#pragma unroll
        for (int i = 0; i < 4; ++i) xv[i] = *(const float4*)&xs[(r0 + i) * 128 + k];
#pragma unroll
        for (int j = 0; j < 4; ++j) wv[j] = *(const float4*)&ws[(k + j) * 64 + cc];
#pragma unroll
        for (int i = 0; i < 4; ++i) {
            acc[i][0] += xv[i].x * wv[0].x + xv[i].y * wv[1].x + xv[i].z * wv[2].x + xv[i].w * wv[3].x;
            acc[i][1] += xv[i].x * wv[0].y + xv[i].y * wv[1].y + xv[i].z * wv[2].y + xv[i].w * wv[3].y;
            acc[i][2] += xv[i].x * wv[0].z + xv[i].y * wv[1].z + xv[i].z * wv[2].z + xv[i].w * wv[3].z;
            acc[i][3] += xv[i].x * wv[0].w + xv[i].y * wv[1].w + xv[i].z * wv[2].w + xv[i].w * wv[3].w;
        }
    }
#pragma unroll
    for (int i = 0; i < 4; ++i) {
        int row = row0 + r0 + i;
        if (row < n) {
            float s = dinv[row];
            ushort4 o;
            o.x = f2bf(s * acc[i][0]);
            o.y = f2bf(s * acc[i][1]);
            o.z = f2bf(s * acc[i][2]);
            o.w = f2bf(s * acc[i][3]);
            *(ushort4*)&Hs[(size_t)row * outc + c0 + cc] = o;
        }
    }
}

// ---- aggregation: out[d] = dinv[d]*(Hs[d] + sum_{s in N(d)} Hs[s]) + b -----
// one wave per node; lane loads 8 bf16 channels (16 B); wave covers
// SLOTS=64*8/C neighbor rows per load instruction; butterfly-reduce slots.

template<int C>
__global__ __launch_bounds__(256) void agg_kernel(
    const unsigned short* __restrict__ Hs, const float* __restrict__ bias,
    const float* __restrict__ dinv, const int* __restrict__ rowptr,
    const int* __restrict__ col, float* __restrict__ out, int n, int relu) {
    constexpr int LPR = C / 8;        // lanes per row
    constexpr int SLOTS = 64 / LPR;   // neighbor rows per wave-load
    int d = (blockIdx.x * 256 + threadIdx.x) >> 6;   // node (wave-uniform)
    if (d >= n) return;
    int lane = threadIdx.x & 63;
    int cl = lane & (LPR - 1);        // channel group: channels [cl*8, cl*8+8)
    int slot = lane / LPR;

    float acc[8] = {0.f, 0.f, 0.f, 0.f, 0.f, 0.f, 0.f, 0.f};
    int beg = rowptr[d], end = rowptr[d + 1];

    for (int j = beg; j < end; j += 2 * SLOTS) {
        int i0 = j + slot, i1 = j + SLOTS + slot;
        uint4 v0 = make_uint4(0, 0, 0, 0), v1 = make_uint4(0, 0, 0, 0);
        if (i0 < end) v0 = *((const uint4*)(Hs + (size_t)col[i0] * C) + cl);
        if (i1 < end) v1 = *((const uint4*)(Hs + (size_t)col[i1] * C) + cl);
        acc[0] += bf_lo(v0.x) + bf_lo(v1.x);
        acc[1] += bf_hi(v0.x) + bf_hi(v1.x);
        acc[2] += bf_lo(v0.y) + bf_lo(v1.y);
        acc[3] += bf_hi(v0.y) + bf_hi(v1.y);
        acc[4] += bf_lo(v0.z) + bf_lo(v1.z);
        acc[5] += bf_hi(v0.z) + bf_hi(v1.z);
        acc[6] += bf_lo(v0.w) + bf_lo(v1.w);
        acc[7] += bf_hi(v0.w) + bf_hi(v1.w);
    }
    // reduce neighbor partial sums across slots (all lanes end with the total)
#pragma unroll
    for (int m = LPR; m < 64; m <<= 1) {
#pragma unroll
        for (int k = 0; k < 8; ++k) acc[k] += __shfl_xor(acc[k], m, 64);
    }
    // self-loop contribution
    uint4 sv = *((const uint4*)(Hs + (size_t)d * C) + cl);
    acc[0] += bf_lo(sv.x); acc[1] += bf_hi(sv.x);
    acc[2] += bf_lo(sv.y); acc[3] += bf_hi(sv.y);
    acc[4] += bf_lo(sv.z); acc[5] += bf_hi(sv.z);
    acc[6] += bf_lo(sv.w); acc[7] += bf_hi(sv.w);

    float dv = dinv[d];
    float4 b0 = *((const float4*)bias + cl * 2);
    float4 b1 = *((const float4*)bias + cl * 2 + 1);
    float r[8];
    r[0] = dv * acc[0] + b0.x; r[1] = dv * acc[1] + b0.y;
    r[2] = dv * acc[2] + b0.z; r[3] = dv * acc[3] + b0.w;
    r[4] = dv * acc[4] + b1.x; r[5] = dv * acc[5] + b1.y;
    r[6] = dv * acc[6] + b1.z; r[7] = dv * acc[7] + b1.w;
    if (relu) {
#pragma unroll
        for (int k = 0; k < 8; ++k) r[k] = fmaxf(r[k], 0.f);
    }
    if (slot == 0) {
        float* o = out + (size_t)d * C + cl * 8;
        *(float4*)o = make_float4(r[0], r[1], r[2], r[3]);
        *(float4*)(o + 4) = make_float4(r[4], r[5], r[6], r[7]);
    }
}

// ---- driver ----------------------------------------------------------------

extern "C" void kernel_launch(void* const* d_in, const int* in_sizes, int n_in,
                              void* d_out, int out_size, void* d_ws, size_t ws_size,
                              hipStream_t stream) {
    const float* x  = (const float*)d_in[0];
    const int*   ei = (const int*)d_in[1];
    const float* W1 = (const float*)d_in[2];
    const float* b1 = (const float*)d_in[3];
    const float* W2 = (const float*)d_in[4];
    const float* b2 = (const float*)d_in[5];
    float* out = (float*)d_out;

    int N = in_sizes[0] / IN_C;
    int E = in_sizes[1] / 2;
    const int* src = ei;
    const int* dst = ei + E;

    int nb = (N + SCAN_ELEMS - 1) / SCAN_ELEMS;

    char* ws = (char*)d_ws;
    size_t off = 0;
    int*   deg    = (int*)(ws + off);   off += (size_t)N * 4;
    int*   cursor = (int*)(ws + off);   off += (size_t)N * 4;   // contiguous with deg
    float* dinv   = (float*)(ws + off); off += (size_t)N * 4;
    int*   rowptr = (int*)(ws + off);   off += (size_t)(N + 1) * 4;
    off = (off + 15) & ~(size_t)15;
    int*   bsum   = (int*)(ws + off);   off += (size_t)(nb + 1) * 4;
    off = (off + 15) & ~(size_t)15;
    int*   col    = (int*)(ws + off);   off += (size_t)E * 4;
    off = (off + 15) & ~(size_t)15;
    unsigned short* H1 = (unsigned short*)(ws + off); off += (size_t)N * HID_C * 2;
    off = (off + 15) & ~(size_t)15;
    float* AG1    = (float*)(ws + off); off += (size_t)N * HID_C * 4;
    unsigned short* H2 = H1;  // H1 dead after agg1; reuse (bf16, 64 cols)

    hipMemsetAsync(deg, 0, (size_t)N * 8, stream);  // zeros deg + cursor

    const int tpb = 256;
    deg_kernel<<<(E + tpb - 1) / tpb, tpb, 0, stream>>>(dst, deg, E);
    dinv_kernel<<<(N + tpb - 1) / tpb, tpb, 0, stream>>>(deg, dinv, N);
    scan1_kernel<<<nb, 256, 0, stream>>>(deg, rowptr, bsum, N);
    scan2_kernel<<<1, 1024, 0, stream>>>(bsum, nb);
    scan3_kernel<<<nb, 256, 0, stream>>>(rowptr, bsum, N, nb);
    scatter_kernel<<<(E + tpb - 1) / tpb, tpb, 0, stream>>>(src, dst, rowptr, cursor, col, E);

    dim3 g1((N + 63) / 64, HID_C / 64);
    mm_kernel<<<g1, 256, 0, stream>>>(x, W1, dinv, H1, N, HID_C);
    agg_kernel<HID_C><<<(N + 3) / 4, 256, 0, stream>>>(H1, b1, dinv, rowptr, col, AG1, N, 1);

    dim3 g2((N + 63) / 64, OUT_C / 64);
    mm_kernel<<<g2, 256, 0, stream>>>(AG1, W2, dinv, H2, N, OUT_C);
    agg_kernel<OUT_C><<<(N + 3) / 4, 256, 0, stream>>>(H2, b2, dinv, rowptr, col, out, N, 0);
}

// Round 6
// 408.046 us; speedup vs baseline: 1.8697x; 1.2398x over previous
//
#include <hip/hip_runtime.h>

#define IN_C  128
#define HID_C 128
#define OUT_C 64
#define NPB      128      // nodes per bucket (pow2)
#define NPB_SH   7
#define NPB_MASK 127
#define MAXB     2048     // max buckets in LDS fast path (N <= 262144)
#define CAP      6144     // pass-2 LDS staging capacity (mean bucket = 2048 edges)
#define B1_CHUNK 8192     // edges per pass-1 block (256 thr x 32)

__device__ __forceinline__ unsigned short f2bf(float f) {
    unsigned u = __float_as_uint(f);
    unsigned r = (u + 0x7FFFu + ((u >> 16) & 1u)) >> 16;
    return (unsigned short)r;
}
__device__ __forceinline__ float bf_lo(unsigned u) { return __uint_as_float(u << 16); }
__device__ __forceinline__ float bf_hi(unsigned u) { return __uint_as_float(u & 0xFFFF0000u); }

// ---- CSR build -------------------------------------------------------------

// global bucket histogram (LDS-aggregated)
__global__ __launch_bounds__(256) void hist_kernel(const int* __restrict__ dst,
                                                   int* __restrict__ bhist,
                                                   int E, int B) {
    __shared__ int lh[MAXB];
    int t = threadIdx.x;
    int e0 = blockIdx.x * B1_CHUNK;
    int nE = min(B1_CHUNK, E - e0);
    if (B <= MAXB) {
        for (int i = t; i < B; i += 256) lh[i] = 0;
        __syncthreads();
        for (int i = t; i < nE; i += 256) atomicAdd(&lh[dst[e0 + i] >> NPB_SH], 1);
        __syncthreads();
        for (int i = t; i < B; i += 256)
            if (lh[i]) atomicAdd(&bhist[i], lh[i]);
    } else {  // fallback (never for this problem size)
        for (int i = t; i < nE; i += 256) atomicAdd(&bhist[dst[e0 + i] >> NPB_SH], 1);
    }
}

// single-block exclusive scan of bucket sums -> bbase[0..B], bcur init
__global__ __launch_bounds__(1024) void scan_bucket_kernel(const int* __restrict__ bhist,
                                                           int* __restrict__ bbase,
                                                           int* __restrict__ bcur, int B) {
    __shared__ int sums[1024];
    int t = threadIdx.x;
    int chunk = (B + 1023) >> 10;
    int beg = t * chunk, end = min(beg + chunk, B);
    int s = 0;
    for (int i = beg; i < end; ++i) s += bhist[i];
    sums[t] = s;
    __syncthreads();
    for (int off = 1; off < 1024; off <<= 1) {
        int v = (t >= off) ? sums[t - off] : 0;
        __syncthreads();
        sums[t] += v;
        __syncthreads();
    }
    int run = (t == 0) ? 0 : sums[t - 1];
    for (int i = beg; i < end; ++i) {
        bbase[i] = run; bcur[i] = run;
        run += bhist[i];
    }
    if (t == 1023) bbase[B] = sums[1023];   // == E
}

// pass 1: two-phase multisplit into bucket-contiguous ebuf (packed entries)
__global__ __launch_bounds__(256) void bucket_kernel(const int* __restrict__ src,
                                                     const int* __restrict__ dst,
                                                     int* __restrict__ bcur,
                                                     int* __restrict__ ebuf,
                                                     int E, int B) {
    __shared__ int hist[MAXB];
    __shared__ int runb[MAXB];
    int t = threadIdx.x;
    int e0 = blockIdx.x * B1_CHUNK;
    int nE = min(B1_CHUNK, E - e0);
    if (B <= MAXB) {
        for (int i = t; i < B; i += 256) hist[i] = 0;
        __syncthreads();
        for (int i = t; i < nE; i += 256) atomicAdd(&hist[dst[e0 + i] >> NPB_SH], 1);
        __syncthreads();
        for (int i = t; i < B; i += 256) {
            int c = hist[i];
            runb[i] = c ? atomicAdd(&bcur[i], c) : 0;
            hist[i] = 0;   // becomes local cursor
        }
        __syncthreads();
        for (int i = t; i < nE; i += 256) {
            int d = dst[e0 + i], s = src[e0 + i];
            int b = d >> NPB_SH;
            int off2 = atomicAdd(&hist[b], 1);
            ebuf[runb[b] + off2] = (s << NPB_SH) | (d & NPB_MASK);
        }
    } else {  // fallback
        for (int i = t; i < nE; i += 256) {
            int d = dst[e0 + i], s = src[e0 + i];
            int pos = atomicAdd(&bcur[d >> NPB_SH], 1);
            ebuf[pos] = (s << NPB_SH) | (d & NPB_MASK);
        }
    }
}

// pass 2: per-bucket counting sort -> col (coalesced), rowptr, dinv
__global__ __launch_bounds__(256) void csr_kernel(const int* __restrict__ ebuf,
                                                  const int* __restrict__ bbase,
                                                  int* __restrict__ col,
                                                  int* __restrict__ rowptr,
                                                  float* __restrict__ dinv,
                                                  int N, int E) {
    __shared__ int sorted[CAP];
    __shared__ int lhist[NPB];
    __shared__ int lpre[NPB + 1];
    int b = blockIdx.x;
    int t = threadIdx.x;
    int base = bbase[b], size = bbase[b + 1] - base;
    int node_base = b << NPB_SH;
    int nn = min(NPB, N - node_base);

    if (t < NPB) lhist[t] = 0;
    __syncthreads();
    for (int i = t; i < size; i += 256) atomicAdd(&lhist[ebuf[base + i] & NPB_MASK], 1);
    __syncthreads();
    // inclusive scan of lhist into lpre[1..NPB], lpre[0]=0
    if (t < NPB) lpre[t + 1] = lhist[t];
    if (t == 0) lpre[0] = 0;
    __syncthreads();
    for (int off = 1; off < NPB; off <<= 1) {
        int v = (t >= off && t < NPB) ? lpre[t + 1 - off] : 0;
        __syncthreads();
        if (t < NPB) lpre[t + 1] += v;
        __syncthreads();
    }
    if (t < nn) {
        rowptr[node_base + t] = base + lpre[t];
        dinv[node_base + t] = rsqrtf((float)(lhist[t] + 1));  // +1 self-loop
    }
    if (node_base + nn == N && t == 0) rowptr[N] = base + size;  // == E on last bucket
    // cursors = exclusive prefix
    if (t < NPB) lhist[t] = lpre[t];
    __syncthreads();
    if (size <= CAP) {
        for (int i = t; i < size; i += 256) {
            int entry = ebuf[base + i];
            int slot = atomicAdd(&lhist[entry & NPB_MASK], 1);
            sorted[slot] = entry >> NPB_SH;
        }
        __syncthreads();
        for (int i = t; i < size; i += 256) col[base + i] = sorted[i];
    } else {  // safety fallback: direct (uncoalesced) placement
        for (int i = t; i < size; i += 256) {
            int entry = ebuf[base + i];
            int slot = atomicAdd(&lhist[entry & NPB_MASK], 1);
            col[base + slot] = entry >> NPB_SH;
        }
    }
}

// ---- dense transform: Hs[r][c] = bf16( dinv[r] * sum_k X[r][k] * W[k][c] ) -

__global__ __launch_bounds__(256) void mm_kernel(
    const float* __restrict__ X, const float* __restrict__ W,
    const float* __restrict__ dinv, unsigned short* __restrict__ Hs,
    int n, int outc) {
    __shared__ float xs[64 * 128];   // 32 KB
    __shared__ float ws[128 * 64];   // 32 KB
    int t = threadIdx.x;
    int row0 = blockIdx.x * 64;
    int c0 = blockIdx.y * 64;

    for (int i = t; i < (64 * 128) / 4; i += 256) {
        int idx = i * 4;
        int r = idx >> 7, k = idx & 127;
        int row = row0 + r;
        float4 v = make_float4(0.f, 0.f, 0.f, 0.f);
        if (row < n) v = *(const float4*)&X[(size_t)row * 128 + k];
        *(float4*)&xs[idx] = v;
    }
    for (int i = t; i < (128 * 64) / 4; i += 256) {
        int idx = i * 4;
        int k = idx >> 6, c = idx & 63;
        *(float4*)&ws[idx] = *(const float4*)&W[(size_t)k * outc + c0 + c];
    }
    __syncthreads();

    int tc = t & 15, tr = t >> 4;
    int r0 = tr * 4, cc = tc * 4;
    float acc[4][4] = {};
    for (int k = 0; k < 128; k += 4) {
        float4 xv[4], wv[4];
#pragma unroll
        for (int i = 0; i < 4; ++i) xv[i] = *(const float4*)&xs[(r0 + i) * 128 + k];
#pragma unroll
        for (int j = 0; j < 4; ++j) wv[j] = *(const float4*)&ws[(k + j) * 64 + cc];
#pragma unroll
        for (int i = 0; i < 4; ++i) {
            acc[i][0] += xv[i].x * wv[0].x + xv[i].y * wv[1].x + xv[i].z * wv[2].x + xv[i].w * wv[3].x;
            acc[i][1] += xv[i].x * wv[0].y + xv[i].y * wv[1].y + xv[i].z * wv[2].y + xv[i].w * wv[3].y;
            acc[i][2] += xv[i].x * wv[0].z + xv[i].y * wv[1].z + xv[i].z * wv[2].z + xv[i].w * wv[3].z;
            acc[i][3] += xv[i].x * wv[0].w + xv[i].y * wv[1].w + xv[i].z * wv[2].w + xv[i].w * wv[3].w;
        }
    }
#pragma unroll
    for (int i = 0; i < 4; ++i) {
        int row = row0 + r0 + i;
        if (row < n) {
            float s = dinv[row];
            ushort4 o;
            o.x = f2bf(s * acc[i][0]);
            o.y = f2bf(s * acc[i][1]);
            o.z = f2bf(s * acc[i][2]);
            o.w = f2bf(s * acc[i][3]);
            *(ushort4*)&Hs[(size_t)row * outc + c0 + cc] = o;
        }
    }
}

// ---- aggregation: out[d] = dinv[d]*(Hs[d] + sum_{s in N(d)} Hs[s]) + b -----

template<int C>
__global__ __launch_bounds__(256) void agg_kernel(
    const unsigned short* __restrict__ Hs, const float* __restrict__ bias,
    const float* __restrict__ dinv, const int* __restrict__ rowptr,
    const int* __restrict__ col, float* __restrict__ out, int n, int relu) {
    constexpr int LPR = C / 8;        // lanes per row
    constexpr int SLOTS = 64 / LPR;   // neighbor rows per wave-load
    int d = (blockIdx.x * 256 + threadIdx.x) >> 6;   // node (wave-uniform)
    if (d >= n) return;
    int lane = threadIdx.x & 63;
    int cl = lane & (LPR - 1);
    int slot = lane / LPR;

    float acc[8] = {0.f, 0.f, 0.f, 0.f, 0.f, 0.f, 0.f, 0.f};
    int beg = rowptr[d], end = rowptr[d + 1];

    for (int j = beg; j < end; j += 2 * SLOTS) {
        int i0 = j + slot, i1 = j + SLOTS + slot;
        uint4 v0 = make_uint4(0, 0, 0, 0), v1 = make_uint4(0, 0, 0, 0);
        if (i0 < end) v0 = *((const uint4*)(Hs + (size_t)col[i0] * C) + cl);
        if (i1 < end) v1 = *((const uint4*)(Hs + (size_t)col[i1] * C) + cl);
        acc[0] += bf_lo(v0.x) + bf_lo(v1.x);
        acc[1] += bf_hi(v0.x) + bf_hi(v1.x);
        acc[2] += bf_lo(v0.y) + bf_lo(v1.y);
        acc[3] += bf_hi(v0.y) + bf_hi(v1.y);
        acc[4] += bf_lo(v0.z) + bf_lo(v1.z);
        acc[5] += bf_hi(v0.z) + bf_hi(v1.z);
        acc[6] += bf_lo(v0.w) + bf_lo(v1.w);
        acc[7] += bf_hi(v0.w) + bf_hi(v1.w);
    }
#pragma unroll
    for (int m = LPR; m < 64; m <<= 1) {
#pragma unroll
        for (int k = 0; k < 8; ++k) acc[k] += __shfl_xor(acc[k], m, 64);
    }
    uint4 sv = *((const uint4*)(Hs + (size_t)d * C) + cl);
    acc[0] += bf_lo(sv.x); acc[1] += bf_hi(sv.x);
    acc[2] += bf_lo(sv.y); acc[3] += bf_hi(sv.y);
    acc[4] += bf_lo(sv.z); acc[5] += bf_hi(sv.z);
    acc[6] += bf_lo(sv.w); acc[7] += bf_hi(sv.w);

    float dv = dinv[d];
    float4 b0 = *((const float4*)bias + cl * 2);
    float4 b1 = *((const float4*)bias + cl * 2 + 1);
    float r[8];
    r[0] = dv * acc[0] + b0.x; r[1] = dv * acc[1] + b0.y;
    r[2] = dv * acc[2] + b0.z; r[3] = dv * acc[3] + b0.w;
    r[4] = dv * acc[4] + b1.x; r[5] = dv * acc[5] + b1.y;
    r[6] = dv * acc[6] + b1.z; r[7] = dv * acc[7] + b1.w;
    if (relu) {
#pragma unroll
        for (int k = 0; k < 8; ++k) r[k] = fmaxf(r[k], 0.f);
    }
    if (slot == 0) {
        float* o = out + (size_t)d * C + cl * 8;
        *(float4*)o = make_float4(r[0], r[1], r[2], r[3]);
        *(float4*)(o + 4) = make_float4(r[4], r[5], r[6], r[7]);
    }
}

// ---- driver ----------------------------------------------------------------

extern "C" void kernel_launch(void* const* d_in, const int* in_sizes, int n_in,
                              void* d_out, int out_size, void* d_ws, size_t ws_size,
                              hipStream_t stream) {
    const float* x  = (const float*)d_in[0];
    const int*   ei = (const int*)d_in[1];
    const float* W1 = (const float*)d_in[2];
    const float* b1 = (const float*)d_in[3];
    const float* W2 = (const float*)d_in[4];
    const float* b2 = (const float*)d_in[5];
    float* out = (float*)d_out;

    int N = in_sizes[0] / IN_C;
    int E = in_sizes[1] / 2;
    const int* src = ei;
    const int* dst = ei + E;
    int B = (N + NPB - 1) >> NPB_SH;   // buckets (782 for N=100k)

    char* ws = (char*)d_ws;
    size_t off = 0;
    int*   bhist  = (int*)(ws + off);   off += (size_t)B * 4;
    int*   bbase  = (int*)(ws + off);   off += (size_t)(B + 1) * 4;
    int*   bcur   = (int*)(ws + off);   off += (size_t)B * 4;
    float* dinv   = (float*)(ws + off); off += (size_t)N * 4;
    int*   rowptr = (int*)(ws + off);   off += (size_t)(N + 1) * 4;
    off = (off + 15) & ~(size_t)15;
    int*   ebuf   = (int*)(ws + off);   off += (size_t)E * 4;
    int*   col    = (int*)(ws + off);   off += (size_t)E * 4;
    off = (off + 15) & ~(size_t)15;
    unsigned short* H1 = (unsigned short*)(ws + off); off += (size_t)N * HID_C * 2;
    off = (off + 15) & ~(size_t)15;
    float* AG1    = (float*)(ws + off); off += (size_t)N * HID_C * 4;
    unsigned short* H2 = H1;  // H1 dead after agg1; reuse (bf16, 64 cols)

    hipMemsetAsync(bhist, 0, (size_t)B * 4, stream);

    int nblk = (E + B1_CHUNK - 1) / B1_CHUNK;
    hist_kernel<<<nblk, 256, 0, stream>>>(dst, bhist, E, B);
    scan_bucket_kernel<<<1, 1024, 0, stream>>>(bhist, bbase, bcur, B);
    bucket_kernel<<<nblk, 256, 0, stream>>>(src, dst, bcur, ebuf, E, B);
    csr_kernel<<<B, 256, 0, stream>>>(ebuf, bbase, col, rowptr, dinv, N, E);

    dim3 g1((N + 63) / 64, HID_C / 64);
    mm_kernel<<<g1, 256, 0, stream>>>(x, W1, dinv, H1, N, HID_C);
    agg_kernel<HID_C><<<(N + 3) / 4, 256, 0, stream>>>(H1, b1, dinv, rowptr, col, AG1, N, 1);

    dim3 g2((N + 63) / 64, OUT_C / 64);
    mm_kernel<<<g2, 256, 0, stream>>>(AG1, W2, dinv, H2, N, OUT_C);
    agg_kernel<OUT_C><<<(N + 3) / 4, 256, 0, stream>>>(H2, b2, dinv, rowptr, col, out, N, 0);
}

// Round 7
// 340.693 us; speedup vs baseline: 2.2393x; 1.1977x over previous
//
#include <hip/hip_runtime.h>

#define IN_C  128
#define HID_C 128
#define OUT_C 64
#define NPB      128      // nodes per bucket (pow2)
#define NPB_SH   7
#define NPB_MASK 127
#define MAXB     2048     // max buckets in LDS fast path (N <= 262144)
#define CAP      6144     // pass-2 LDS staging capacity
#define B1_CHUNK 8192     // edges per pass-1 block

typedef __attribute__((ext_vector_type(8))) short short8;
typedef __attribute__((ext_vector_type(4))) float f32x4;

__device__ __forceinline__ unsigned short f2bf(float f) {
    unsigned u = __float_as_uint(f);
    unsigned r = (u + 0x7FFFu + ((u >> 16) & 1u)) >> 16;
    return (unsigned short)r;
}
__device__ __forceinline__ float bf_lo(unsigned u) { return __uint_as_float(u << 16); }
__device__ __forceinline__ float bf_hi(unsigned u) { return __uint_as_float(u & 0xFFFF0000u); }

// ---- CSR build -------------------------------------------------------------

__global__ __launch_bounds__(256) void hist_kernel(const int* __restrict__ dst,
                                                   int* __restrict__ bhist,
                                                   int E, int B) {
    __shared__ int lh[MAXB];
    int t = threadIdx.x;
    int e0 = blockIdx.x * B1_CHUNK;
    int nE = min(B1_CHUNK, E - e0);
    if (B <= MAXB) {
        for (int i = t; i < B; i += 256) lh[i] = 0;
        __syncthreads();
        for (int i = t; i < nE; i += 256) atomicAdd(&lh[dst[e0 + i] >> NPB_SH], 1);
        __syncthreads();
        for (int i = t; i < B; i += 256)
            if (lh[i]) atomicAdd(&bhist[i], lh[i]);
    } else {
        for (int i = t; i < nE; i += 256) atomicAdd(&bhist[dst[e0 + i] >> NPB_SH], 1);
    }
}

__global__ __launch_bounds__(1024) void scan_bucket_kernel(const int* __restrict__ bhist,
                                                           int* __restrict__ bbase,
                                                           int* __restrict__ bcur, int B) {
    __shared__ int sums[1024];
    int t = threadIdx.x;
    int chunk = (B + 1023) >> 10;
    int beg = t * chunk, end = min(beg + chunk, B);
    int s = 0;
    for (int i = beg; i < end; ++i) s += bhist[i];
    sums[t] = s;
    __syncthreads();
    for (int off = 1; off < 1024; off <<= 1) {
        int v = (t >= off) ? sums[t - off] : 0;
        __syncthreads();
        sums[t] += v;
        __syncthreads();
    }
    int run = (t == 0) ? 0 : sums[t - 1];
    for (int i = beg; i < end; ++i) {
        bbase[i] = run; bcur[i] = run;
        run += bhist[i];
    }
    if (t == 1023) bbase[B] = sums[1023];
}

__global__ __launch_bounds__(256) void bucket_kernel(const int* __restrict__ src,
                                                     const int* __restrict__ dst,
                                                     int* __restrict__ bcur,
                                                     int* __restrict__ ebuf,
                                                     int E, int B) {
    __shared__ int hist[MAXB];
    __shared__ int runb[MAXB];
    int t = threadIdx.x;
    int e0 = blockIdx.x * B1_CHUNK;
    int nE = min(B1_CHUNK, E - e0);
    if (B <= MAXB) {
        for (int i = t; i < B; i += 256) hist[i] = 0;
        __syncthreads();
        for (int i = t; i < nE; i += 256) atomicAdd(&hist[dst[e0 + i] >> NPB_SH], 1);
        __syncthreads();
        for (int i = t; i < B; i += 256) {
            int c = hist[i];
            runb[i] = c ? atomicAdd(&bcur[i], c) : 0;
            hist[i] = 0;
        }
        __syncthreads();
        for (int i = t; i < nE; i += 256) {
            int d = dst[e0 + i], s = src[e0 + i];
            int b = d >> NPB_SH;
            int off2 = atomicAdd(&hist[b], 1);
            ebuf[runb[b] + off2] = (s << NPB_SH) | (d & NPB_MASK);
        }
    } else {
        for (int i = t; i < nE; i += 256) {
            int d = dst[e0 + i], s = src[e0 + i];
            int pos = atomicAdd(&bcur[d >> NPB_SH], 1);
            ebuf[pos] = (s << NPB_SH) | (d & NPB_MASK);
        }
    }
}

__global__ __launch_bounds__(256) void csr_kernel(const int* __restrict__ ebuf,
                                                  const int* __restrict__ bbase,
                                                  int* __restrict__ col,
                                                  int* __restrict__ rowptr,
                                                  float* __restrict__ dinv,
                                                  int N, int E) {
    __shared__ int sorted[CAP];
    __shared__ int lhist[NPB];
    __shared__ int lpre[NPB + 1];
    int b = blockIdx.x;
    int t = threadIdx.x;
    int base = bbase[b], size = bbase[b + 1] - base;
    int node_base = b << NPB_SH;
    int nn = min(NPB, N - node_base);

    if (t < NPB) lhist[t] = 0;
    __syncthreads();
    for (int i = t; i < size; i += 256) atomicAdd(&lhist[ebuf[base + i] & NPB_MASK], 1);
    __syncthreads();
    if (t < NPB) lpre[t + 1] = lhist[t];
    if (t == 0) lpre[0] = 0;
    __syncthreads();
    for (int off = 1; off < NPB; off <<= 1) {
        int v = (t >= off && t < NPB) ? lpre[t + 1 - off] : 0;
        __syncthreads();
        if (t < NPB) lpre[t + 1] += v;
        __syncthreads();
    }
    if (t < nn) {
        rowptr[node_base + t] = base + lpre[t];
        dinv[node_base + t] = rsqrtf((float)(lhist[t] + 1));
    }
    if (node_base + nn == N && t == 0) rowptr[N] = base + size;
    if (t < NPB) lhist[t] = lpre[t];
    __syncthreads();
    if (size <= CAP) {
        for (int i = t; i < size; i += 256) {
            int entry = ebuf[base + i];
            int slot = atomicAdd(&lhist[entry & NPB_MASK], 1);
            sorted[slot] = entry >> NPB_SH;
        }
        __syncthreads();
        for (int i = t; i < size; i += 256) col[base + i] = sorted[i];
    } else {
        for (int i = t; i < size; i += 256) {
            int entry = ebuf[base + i];
            int slot = atomicAdd(&lhist[entry & NPB_MASK], 1);
            col[base + slot] = entry >> NPB_SH;
        }
    }
}

// ---- MFMA dense transform: Hs[r][c] = bf16(dinv[r] * sum_k A[r][k]*W[k][c])
// K = 128 fixed. A: fp32 (layer1) or bf16 (layer2), read direct from global in
// the A-fragment layout (m=lane&15, k=quad*8+j). W: fp32 [K][C] transposed to
// bf16 LDS [C][136] once per block (272 B row stride: 16B-aligned, 2-way-free
// bank pattern for ds_read_b128). 4 waves x 16 rows = 64 rows/block.

template<int C, typename InT>
__global__ __launch_bounds__(256) void mm_mfma_kernel(
    const InT* __restrict__ X, const float* __restrict__ W,
    const float* __restrict__ dinv, unsigned short* __restrict__ Hs, int n) {
    constexpr int LD = 136;               // padded K (shorts); 272 B stride
    __shared__ unsigned short Wt[C][LD];
    int t = threadIdx.x;

    // stage W^T as bf16
    for (int i = t; i < (128 * C) / 4; i += 256) {
        int idx = i * 4;
        int k = idx / C, c = idx % C;
        float4 wv = *(const float4*)&W[(size_t)k * C + c];
        Wt[c + 0][k] = f2bf(wv.x);
        Wt[c + 1][k] = f2bf(wv.y);
        Wt[c + 2][k] = f2bf(wv.z);
        Wt[c + 3][k] = f2bf(wv.w);
    }
    __syncthreads();

    int w = t >> 6, lane = t & 63;
    int m = lane & 15, quad = lane >> 4;
    int row0 = blockIdx.x * 64 + w * 16;
    int arow = min(row0 + m, n - 1);      // clamped A-row (stores are guarded)

    constexpr int NT = C / 16;
    f32x4 acc[NT];
#pragma unroll
    for (int ct = 0; ct < NT; ++ct) acc[ct] = (f32x4){0.f, 0.f, 0.f, 0.f};

#pragma unroll
    for (int kk = 0; kk < 4; ++kk) {
        int k0 = kk * 32 + quad * 8;
        short8 a;
        if constexpr (sizeof(InT) == 4) {   // fp32 input -> convert
            const float* xp = (const float*)X + (size_t)arow * 128 + k0;
            float4 f0 = *(const float4*)xp;
            float4 f1 = *(const float4*)(xp + 4);
            a[0] = (short)f2bf(f0.x); a[1] = (short)f2bf(f0.y);
            a[2] = (short)f2bf(f0.z); a[3] = (short)f2bf(f0.w);
            a[4] = (short)f2bf(f1.x); a[5] = (short)f2bf(f1.y);
            a[6] = (short)f2bf(f1.z); a[7] = (short)f2bf(f1.w);
        } else {                            // bf16 input -> direct 16B load
            a = *(const short8*)((const unsigned short*)X + (size_t)arow * 128 + k0);
        }
#pragma unroll
        for (int ct = 0; ct < NT; ++ct) {
            short8 b = *(const short8*)&Wt[ct * 16 + m][k0];
            acc[ct] = __builtin_amdgcn_mfma_f32_16x16x32_bf16(a, b, acc[ct], 0, 0, 0);
        }
    }

    // epilogue: C/D layout col=lane&15, row=quad*4+reg
    int qrow = row0 + quad * 4;
    float dv[4];
#pragma unroll
    for (int r = 0; r < 4; ++r) dv[r] = (qrow + r < n) ? dinv[qrow + r] : 0.f;
#pragma unroll
    for (int ct = 0; ct < NT; ++ct) {
        int c = ct * 16 + m;
#pragma unroll
        for (int r = 0; r < 4; ++r) {
            int row = qrow + r;
            if (row < n) Hs[(size_t)row * C + c] = f2bf(acc[ct][r] * dv[r]);
        }
    }
}

// ---- aggregation: out[d] = dinv[d]*(Hs[d] + sum_{s in N(d)} Hs[s]) + b -----

template<int C, bool BOUT>
__global__ __launch_bounds__(256) void agg_kernel(
    const unsigned short* __restrict__ Hs, const float* __restrict__ bias,
    const float* __restrict__ dinv, const int* __restrict__ rowptr,
    const int* __restrict__ col, void* __restrict__ outv, int n, int relu) {
    constexpr int LPR = C / 8;
    constexpr int SLOTS = 64 / LPR;
    int d = (blockIdx.x * 256 + threadIdx.x) >> 6;
    if (d >= n) return;
    int lane = threadIdx.x & 63;
    int cl = lane & (LPR - 1);
    int slot = lane / LPR;

    float acc[8] = {0.f, 0.f, 0.f, 0.f, 0.f, 0.f, 0.f, 0.f};
    int beg = rowptr[d], end = rowptr[d + 1];

    for (int j = beg; j < end; j += 2 * SLOTS) {
        int i0 = j + slot, i1 = j + SLOTS + slot;
        uint4 v0 = make_uint4(0, 0, 0, 0), v1 = make_uint4(0, 0, 0, 0);
        if (i0 < end) v0 = *((const uint4*)(Hs + (size_t)col[i0] * C) + cl);
        if (i1 < end) v1 = *((const uint4*)(Hs + (size_t)col[i1] * C) + cl);
        acc[0] += bf_lo(v0.x) + bf_lo(v1.x);
        acc[1] += bf_hi(v0.x) + bf_hi(v1.x);
        acc[2] += bf_lo(v0.y) + bf_lo(v1.y);
        acc[3] += bf_hi(v0.y) + bf_hi(v1.y);
        acc[4] += bf_lo(v0.z) + bf_lo(v1.z);
        acc[5] += bf_hi(v0.z) + bf_hi(v1.z);
        acc[6] += bf_lo(v0.w) + bf_lo(v1.w);
        acc[7] += bf_hi(v0.w) + bf_hi(v1.w);
    }
#pragma unroll
    for (int mk = LPR; mk < 64; mk <<= 1) {
#pragma unroll
        for (int k = 0; k < 8; ++k) acc[k] += __shfl_xor(acc[k], mk, 64);
    }
    uint4 sv = *((const uint4*)(Hs + (size_t)d * C) + cl);
    acc[0] += bf_lo(sv.x); acc[1] += bf_hi(sv.x);
    acc[2] += bf_lo(sv.y); acc[3] += bf_hi(sv.y);
    acc[4] += bf_lo(sv.z); acc[5] += bf_hi(sv.z);
    acc[6] += bf_lo(sv.w); acc[7] += bf_hi(sv.w);

    float dv = dinv[d];
    float4 b0 = *((const float4*)bias + cl * 2);
    float4 b1 = *((const float4*)bias + cl * 2 + 1);
    float r[8];
    r[0] = dv * acc[0] + b0.x; r[1] = dv * acc[1] + b0.y;
    r[2] = dv * acc[2] + b0.z; r[3] = dv * acc[3] + b0.w;
    r[4] = dv * acc[4] + b1.x; r[5] = dv * acc[5] + b1.y;
    r[6] = dv * acc[6] + b1.z; r[7] = dv * acc[7] + b1.w;
    if (relu) {
#pragma unroll
        for (int k = 0; k < 8; ++k) r[k] = fmaxf(r[k], 0.f);
    }
    if (slot == 0) {
        if constexpr (BOUT) {   // bf16 output (feeds next mm)
            uint4 o;
            o.x = (unsigned)f2bf(r[0]) | ((unsigned)f2bf(r[1]) << 16);
            o.y = (unsigned)f2bf(r[2]) | ((unsigned)f2bf(r[3]) << 16);
            o.z = (unsigned)f2bf(r[4]) | ((unsigned)f2bf(r[5]) << 16);
            o.w = (unsigned)f2bf(r[6]) | ((unsigned)f2bf(r[7]) << 16);
            *(uint4*)((unsigned short*)outv + (size_t)d * C + cl * 8) = o;
        } else {                // fp32 final output
            float* o = (float*)outv + (size_t)d * C + cl * 8;
            *(float4*)o = make_float4(r[0], r[1], r[2], r[3]);
            *(float4*)(o + 4) = make_float4(r[4], r[5], r[6], r[7]);
        }
    }
}

// ---- driver ----------------------------------------------------------------

extern "C" void kernel_launch(void* const* d_in, const int* in_sizes, int n_in,
                              void* d_out, int out_size, void* d_ws, size_t ws_size,
                              hipStream_t stream) {
    const float* x  = (const float*)d_in[0];
    const int*   ei = (const int*)d_in[1];
    const float* W1 = (const float*)d_in[2];
    const float* b1 = (const float*)d_in[3];
    const float* W2 = (const float*)d_in[4];
    const float* b2 = (const float*)d_in[5];
    float* out = (float*)d_out;

    int N = in_sizes[0] / IN_C;
    int E = in_sizes[1] / 2;
    const int* src = ei;
    const int* dst = ei + E;
    int B = (N + NPB - 1) >> NPB_SH;

    char* ws = (char*)d_ws;
    size_t off = 0;
    int*   bhist  = (int*)(ws + off);   off += (size_t)B * 4;
    int*   bbase  = (int*)(ws + off);   off += (size_t)(B + 1) * 4;
    int*   bcur   = (int*)(ws + off);   off += (size_t)B * 4;
    float* dinv   = (float*)(ws + off); off += (size_t)N * 4;
    int*   rowptr = (int*)(ws + off);   off += (size_t)(N + 1) * 4;
    off = (off + 15) & ~(size_t)15;
    int*   ebuf   = (int*)(ws + off);   off += (size_t)E * 4;
    int*   col    = (int*)(ws + off);   off += (size_t)E * 4;
    off = (off + 15) & ~(size_t)15;
    unsigned short* H1  = (unsigned short*)(ws + off); off += (size_t)N * HID_C * 2;
    off = (off + 15) & ~(size_t)15;
    unsigned short* AG1 = (unsigned short*)(ws + off); off += (size_t)N * HID_C * 2;
    unsigned short* H2 = H1;   // H1 dead after agg1; reuse for layer-2 transform

    hipMemsetAsync(bhist, 0, (size_t)B * 4, stream);

    int nblk = (E + B1_CHUNK - 1) / B1_CHUNK;
    hist_kernel<<<nblk, 256, 0, stream>>>(dst, bhist, E, B);
    scan_bucket_kernel<<<1, 1024, 0, stream>>>(bhist, bbase, bcur, B);
    bucket_kernel<<<nblk, 256, 0, stream>>>(src, dst, bcur, ebuf, E, B);
    csr_kernel<<<B, 256, 0, stream>>>(ebuf, bbase, col, rowptr, dinv, N, E);

    int mblk = (N + 63) / 64;
    mm_mfma_kernel<HID_C, float><<<mblk, 256, 0, stream>>>(x, W1, dinv, H1, N);
    agg_kernel<HID_C, true><<<(N + 3) / 4, 256, 0, stream>>>(H1, b1, dinv, rowptr, col, AG1, N, 1);

    mm_mfma_kernel<OUT_C, unsigned short><<<mblk, 256, 0, stream>>>(AG1, W2, dinv, H2, N);
    agg_kernel<OUT_C, false><<<(N + 3) / 4, 256, 0, stream>>>(H2, b2, dinv, rowptr, col, out, N, 0);
}

// Round 8
// 327.694 us; speedup vs baseline: 2.3281x; 1.0397x over previous
//
#include <hip/hip_runtime.h>

#define IN_C  128
#define HID_C 128
#define OUT_C 64
#define NPB      128      // nodes per bucket (pow2)
#define NPB_SH   7
#define NPB_MASK 127
#define MAXB     2048     // max buckets in LDS fast path (N <= 262144)
#define CAP      6144     // pass-2 LDS staging capacity
#define B1_CHUNK 8192     // edges per pass-1 block

typedef __attribute__((ext_vector_type(8))) short short8;
typedef __attribute__((ext_vector_type(4))) float f32x4;

__device__ __forceinline__ unsigned short f2bf(float f) {
    unsigned u = __float_as_uint(f);
    unsigned r = (u + 0x7FFFu + ((u >> 16) & 1u)) >> 16;
    return (unsigned short)r;
}
__device__ __forceinline__ float bf_lo(unsigned u) { return __uint_as_float(u << 16); }
__device__ __forceinline__ float bf_hi(unsigned u) { return __uint_as_float(u & 0xFFFF0000u); }

// ---- CSR build -------------------------------------------------------------

__global__ __launch_bounds__(256) void hist_kernel(const int* __restrict__ dst,
                                                   int* __restrict__ bhist,
                                                   int E, int B) {
    __shared__ int lh[MAXB];
    int t = threadIdx.x;
    int e0 = blockIdx.x * B1_CHUNK;
    int nE = min(B1_CHUNK, E - e0);
    if (B <= MAXB) {
        for (int i = t; i < B; i += 256) lh[i] = 0;
        __syncthreads();
        for (int i = t; i < nE; i += 256) atomicAdd(&lh[dst[e0 + i] >> NPB_SH], 1);
        __syncthreads();
        for (int i = t; i < B; i += 256)
            if (lh[i]) atomicAdd(&bhist[i], lh[i]);
    } else {
        for (int i = t; i < nE; i += 256) atomicAdd(&bhist[dst[e0 + i] >> NPB_SH], 1);
    }
}

__global__ __launch_bounds__(1024) void scan_bucket_kernel(const int* __restrict__ bhist,
                                                           int* __restrict__ bbase,
                                                           int* __restrict__ bcur, int B) {
    __shared__ int sums[1024];
    int t = threadIdx.x;
    int chunk = (B + 1023) >> 10;
    int beg = t * chunk, end = min(beg + chunk, B);
    int s = 0;
    for (int i = beg; i < end; ++i) s += bhist[i];
    sums[t] = s;
    __syncthreads();
    for (int off = 1; off < 1024; off <<= 1) {
        int v = (t >= off) ? sums[t - off] : 0;
        __syncthreads();
        sums[t] += v;
        __syncthreads();
    }
    int run = (t == 0) ? 0 : sums[t - 1];
    for (int i = beg; i < end; ++i) {
        bbase[i] = run; bcur[i] = run;
        run += bhist[i];
    }
    if (t == 1023) bbase[B] = sums[1023];
}

__global__ __launch_bounds__(256) void bucket_kernel(const int* __restrict__ src,
                                                     const int* __restrict__ dst,
                                                     int* __restrict__ bcur,
                                                     int* __restrict__ ebuf,
                                                     int E, int B) {
    __shared__ int hist[MAXB];
    __shared__ int runb[MAXB];
    int t = threadIdx.x;
    int e0 = blockIdx.x * B1_CHUNK;
    int nE = min(B1_CHUNK, E - e0);
    if (B <= MAXB) {
        for (int i = t; i < B; i += 256) hist[i] = 0;
        __syncthreads();
        for (int i = t; i < nE; i += 256) atomicAdd(&hist[dst[e0 + i] >> NPB_SH], 1);
        __syncthreads();
        for (int i = t; i < B; i += 256) {
            int c = hist[i];
            runb[i] = c ? atomicAdd(&bcur[i], c) : 0;
            hist[i] = 0;
        }
        __syncthreads();
        for (int i = t; i < nE; i += 256) {
            int d = dst[e0 + i], s = src[e0 + i];
            int b = d >> NPB_SH;
            int off2 = atomicAdd(&hist[b], 1);
            ebuf[runb[b] + off2] = (s << NPB_SH) | (d & NPB_MASK);
        }
    } else {
        for (int i = t; i < nE; i += 256) {
            int d = dst[e0 + i], s = src[e0 + i];
            int pos = atomicAdd(&bcur[d >> NPB_SH], 1);
            ebuf[pos] = (s << NPB_SH) | (d & NPB_MASK);
        }
    }
}

__global__ __launch_bounds__(256) void csr_kernel(const int* __restrict__ ebuf,
                                                  const int* __restrict__ bbase,
                                                  int* __restrict__ col,
                                                  int* __restrict__ rowptr,
                                                  float* __restrict__ dinv,
                                                  int N, int E) {
    __shared__ int sorted[CAP];
    __shared__ int lhist[NPB];
    __shared__ int lpre[NPB + 1];
    int b = blockIdx.x;
    int t = threadIdx.x;
    int base = bbase[b], size = bbase[b + 1] - base;
    int node_base = b << NPB_SH;
    int nn = min(NPB, N - node_base);

    if (t < NPB) lhist[t] = 0;
    __syncthreads();
    for (int i = t; i < size; i += 256) atomicAdd(&lhist[ebuf[base + i] & NPB_MASK], 1);
    __syncthreads();
    if (t < NPB) lpre[t + 1] = lhist[t];
    if (t == 0) lpre[0] = 0;
    __syncthreads();
    for (int off = 1; off < NPB; off <<= 1) {
        int v = (t >= off && t < NPB) ? lpre[t + 1 - off] : 0;
        __syncthreads();
        if (t < NPB) lpre[t + 1] += v;
        __syncthreads();
    }
    if (t < nn) {
        rowptr[node_base + t] = base + lpre[t];
        dinv[node_base + t] = rsqrtf((float)(lhist[t] + 1));
    }
    if (node_base + nn == N && t == 0) rowptr[N] = base + size;
    if (t < NPB) lhist[t] = lpre[t];
    __syncthreads();
    if (size <= CAP) {
        for (int i = t; i < size; i += 256) {
            int entry = ebuf[base + i];
            int slot = atomicAdd(&lhist[entry & NPB_MASK], 1);
            sorted[slot] = entry >> NPB_SH;
        }
        __syncthreads();
        for (int i = t; i < size; i += 256) col[base + i] = sorted[i];
    } else {
        for (int i = t; i < size; i += 256) {
            int entry = ebuf[base + i];
            int slot = atomicAdd(&lhist[entry & NPB_MASK], 1);
            col[base + slot] = entry >> NPB_SH;
        }
    }
}

// ---- MFMA dense transform --------------------------------------------------

template<int C, typename InT>
__global__ __launch_bounds__(256) void mm_mfma_kernel(
    const InT* __restrict__ X, const float* __restrict__ W,
    const float* __restrict__ dinv, unsigned short* __restrict__ Hs, int n) {
    constexpr int LD = 136;
    __shared__ unsigned short Wt[C][LD];
    int t = threadIdx.x;

    for (int i = t; i < (128 * C) / 4; i += 256) {
        int idx = i * 4;
        int k = idx / C, c = idx % C;
        float4 wv = *(const float4*)&W[(size_t)k * C + c];
        Wt[c + 0][k] = f2bf(wv.x);
        Wt[c + 1][k] = f2bf(wv.y);
        Wt[c + 2][k] = f2bf(wv.z);
        Wt[c + 3][k] = f2bf(wv.w);
    }
    __syncthreads();

    int w = t >> 6, lane = t & 63;
    int m = lane & 15, quad = lane >> 4;
    int row0 = blockIdx.x * 64 + w * 16;
    int arow = min(row0 + m, n - 1);

    constexpr int NT = C / 16;
    f32x4 acc[NT];
#pragma unroll
    for (int ct = 0; ct < NT; ++ct) acc[ct] = (f32x4){0.f, 0.f, 0.f, 0.f};

#pragma unroll
    for (int kk = 0; kk < 4; ++kk) {
        int k0 = kk * 32 + quad * 8;
        short8 a;
        if constexpr (sizeof(InT) == 4) {
            const float* xp = (const float*)X + (size_t)arow * 128 + k0;
            float4 f0 = *(const float4*)xp;
            float4 f1 = *(const float4*)(xp + 4);
            a[0] = (short)f2bf(f0.x); a[1] = (short)f2bf(f0.y);
            a[2] = (short)f2bf(f0.z); a[3] = (short)f2bf(f0.w);
            a[4] = (short)f2bf(f1.x); a[5] = (short)f2bf(f1.y);
            a[6] = (short)f2bf(f1.z); a[7] = (short)f2bf(f1.w);
        } else {
            a = *(const short8*)((const unsigned short*)X + (size_t)arow * 128 + k0);
        }
#pragma unroll
        for (int ct = 0; ct < NT; ++ct) {
            short8 b = *(const short8*)&Wt[ct * 16 + m][k0];
            acc[ct] = __builtin_amdgcn_mfma_f32_16x16x32_bf16(a, b, acc[ct], 0, 0, 0);
        }
    }

    int qrow = row0 + quad * 4;
    float dv[4];
#pragma unroll
    for (int r = 0; r < 4; ++r) dv[r] = (qrow + r < n) ? dinv[qrow + r] : 0.f;
#pragma unroll
    for (int ct = 0; ct < NT; ++ct) {
        int c = ct * 16 + m;
#pragma unroll
        for (int r = 0; r < 4; ++r) {
            int row = qrow + r;
            if (row < n) Hs[(size_t)row * C + c] = f2bf(acc[ct][r] * dv[r]);
        }
    }
}

// ---- aggregation: out[d] = dinv[d]*(Hs[d] + sum_{s in N(d)} Hs[s]) + b -----
// wave per node. col indices prefetched 64-at-a-time into a register
// (coalesced), gather addresses derived via __shfl -> index load is off the
// per-gather critical path. Gathers issued in batches of 4 independent uint4
// loads before any accumulation (4 KB in flight per wave).

template<int C, bool BOUT>
__global__ __launch_bounds__(256) void agg_kernel(
    const unsigned short* __restrict__ Hs, const float* __restrict__ bias,
    const float* __restrict__ dinv, const int* __restrict__ rowptr,
    const int* __restrict__ col, void* __restrict__ outv, int n, int relu) {
    constexpr int LPR = C / 8;        // lanes per row
    constexpr int SLOTS = 64 / LPR;   // rows gathered per wave-load
    int d = (blockIdx.x * 256 + threadIdx.x) >> 6;
    if (d >= n) return;
    int lane = threadIdx.x & 63;
    int cl = lane & (LPR - 1);
    int slot = lane / LPR;

    float acc[8] = {0.f, 0.f, 0.f, 0.f, 0.f, 0.f, 0.f, 0.f};
    int beg = rowptr[d], end = rowptr[d + 1];

    for (int j0 = beg; j0 < end; j0 += 64) {
        int cnt = min(64, end - j0);
        int colv = (j0 + lane < end) ? col[j0 + lane] : 0;
        int groups = (cnt + SLOTS - 1) / SLOTS;
        for (int g = 0; g < groups; g += 4) {
            uint4 v[4];
#pragma unroll
            for (int b = 0; b < 4; ++b) {
                int e = (g + b) * SLOTS + slot;
                int idx = __shfl(colv, e & 63, 64);
                bool ok = (g + b < groups) && (e < cnt);
                v[b] = ok ? *((const uint4*)(Hs + (size_t)idx * C) + cl)
                          : make_uint4(0, 0, 0, 0);
            }
#pragma unroll
            for (int b = 0; b < 4; ++b) {
                acc[0] += bf_lo(v[b].x); acc[1] += bf_hi(v[b].x);
                acc[2] += bf_lo(v[b].y); acc[3] += bf_hi(v[b].y);
                acc[4] += bf_lo(v[b].z); acc[5] += bf_hi(v[b].z);
                acc[6] += bf_lo(v[b].w); acc[7] += bf_hi(v[b].w);
            }
        }
    }
#pragma unroll
    for (int mk = LPR; mk < 64; mk <<= 1) {
#pragma unroll
        for (int k = 0; k < 8; ++k) acc[k] += __shfl_xor(acc[k], mk, 64);
    }
    uint4 sv = *((const uint4*)(Hs + (size_t)d * C) + cl);
    acc[0] += bf_lo(sv.x); acc[1] += bf_hi(sv.x);
    acc[2] += bf_lo(sv.y); acc[3] += bf_hi(sv.y);
    acc[4] += bf_lo(sv.z); acc[5] += bf_hi(sv.z);
    acc[6] += bf_lo(sv.w); acc[7] += bf_hi(sv.w);

    float dv = dinv[d];
    float4 b0 = *((const float4*)bias + cl * 2);
    float4 b1 = *((const float4*)bias + cl * 2 + 1);
    float r[8];
    r[0] = dv * acc[0] + b0.x; r[1] = dv * acc[1] + b0.y;
    r[2] = dv * acc[2] + b0.z; r[3] = dv * acc[3] + b0.w;
    r[4] = dv * acc[4] + b1.x; r[5] = dv * acc[5] + b1.y;
    r[6] = dv * acc[6] + b1.z; r[7] = dv * acc[7] + b1.w;
    if (relu) {
#pragma unroll
        for (int k = 0; k < 8; ++k) r[k] = fmaxf(r[k], 0.f);
    }
    if (slot == 0) {
        if constexpr (BOUT) {
            uint4 o;
            o.x = (unsigned)f2bf(r[0]) | ((unsigned)f2bf(r[1]) << 16);
            o.y = (unsigned)f2bf(r[2]) | ((unsigned)f2bf(r[3]) << 16);
            o.z = (unsigned)f2bf(r[4]) | ((unsigned)f2bf(r[5]) << 16);
            o.w = (unsigned)f2bf(r[6]) | ((unsigned)f2bf(r[7]) << 16);
            *(uint4*)((unsigned short*)outv + (size_t)d * C + cl * 8) = o;
        } else {
            float* o = (float*)outv + (size_t)d * C + cl * 8;
            *(float4*)o = make_float4(r[0], r[1], r[2], r[3]);
            *(float4*)(o + 4) = make_float4(r[4], r[5], r[6], r[7]);
        }
    }
}

// ---- driver ----------------------------------------------------------------

extern "C" void kernel_launch(void* const* d_in, const int* in_sizes, int n_in,
                              void* d_out, int out_size, void* d_ws, size_t ws_size,
                              hipStream_t stream) {
    const float* x  = (const float*)d_in[0];
    const int*   ei = (const int*)d_in[1];
    const float* W1 = (const float*)d_in[2];
    const float* b1 = (const float*)d_in[3];
    const float* W2 = (const float*)d_in[4];
    const float* b2 = (const float*)d_in[5];
    float* out = (float*)d_out;

    int N = in_sizes[0] / IN_C;
    int E = in_sizes[1] / 2;
    const int* src = ei;
    const int* dst = ei + E;
    int B = (N + NPB - 1) >> NPB_SH;

    char* ws = (char*)d_ws;
    size_t off = 0;
    int*   bhist  = (int*)(ws + off);   off += (size_t)B * 4;
    int*   bbase  = (int*)(ws + off);   off += (size_t)(B + 1) * 4;
    int*   bcur   = (int*)(ws + off);   off += (size_t)B * 4;
    float* dinv   = (float*)(ws + off); off += (size_t)N * 4;
    int*   rowptr = (int*)(ws + off);   off += (size_t)(N + 1) * 4;
    off = (off + 15) & ~(size_t)15;
    int*   ebuf   = (int*)(ws + off);   off += (size_t)E * 4;
    int*   col    = (int*)(ws + off);   off += (size_t)E * 4;
    off = (off + 15) & ~(size_t)15;
    unsigned short* H1  = (unsigned short*)(ws + off); off += (size_t)N * HID_C * 2;
    off = (off + 15) & ~(size_t)15;
    unsigned short* AG1 = (unsigned short*)(ws + off); off += (size_t)N * HID_C * 2;
    unsigned short* H2 = H1;

    hipMemsetAsync(bhist, 0, (size_t)B * 4, stream);

    int nblk = (E + B1_CHUNK - 1) / B1_CHUNK;
    hist_kernel<<<nblk, 256, 0, stream>>>(dst, bhist, E, B);
    scan_bucket_kernel<<<1, 1024, 0, stream>>>(bhist, bbase, bcur, B);
    bucket_kernel<<<nblk, 256, 0, stream>>>(src, dst, bcur, ebuf, E, B);
    csr_kernel<<<B, 256, 0, stream>>>(ebuf, bbase, col, rowptr, dinv, N, E);

    int mblk = (N + 63) / 64;
    mm_mfma_kernel<HID_C, float><<<mblk, 256, 0, stream>>>(x, W1, dinv, H1, N);
    agg_kernel<HID_C, true><<<(N + 3) / 4, 256, 0, stream>>>(H1, b1, dinv, rowptr, col, AG1, N, 1);

    mm_mfma_kernel<OUT_C, unsigned short><<<mblk, 256, 0, stream>>>(AG1, W2, dinv, H2, N);
    agg_kernel<OUT_C, false><<<(N + 3) / 4, 256, 0, stream>>>(H2, b2, dinv, rowptr, col, out, N, 0);
}